// Round 7
// baseline (438.891 us; speedup 1.0000x reference)
//
#include <hip/hip_runtime.h>

#define ND 256       // embedding dim
#define NK 512       // centroids
#define LM2 0.0625f  // lambda^2
#define DELTA 0.25f  // approx top-2 gap below this -> exact fp32 rescore

typedef _Float16 f16x8 __attribute__((ext_vector_type(8)));
typedef float f32x4 __attribute__((ext_vector_type(4)));
typedef unsigned short u16x8 __attribute__((ext_vector_type(8)));
typedef unsigned short u16x4 __attribute__((ext_vector_type(4)));
typedef unsigned long long u64;

// ---------------- prep: csq[k] and fp16 centroids in MFMA-B-fragment order ----
// Cf layout: [colblk 4][(ks*4+l4) 32][col 128][8 halves] (16B granule = one
// lane's B-frag slice). Unchanged from r6 (verified: 0 bank conflicts, absmax 0).
__global__ __launch_bounds__(64) void prep_kernel(const float* __restrict__ Cg,
                                                  float* __restrict__ csq,
                                                  unsigned short* __restrict__ Cf) {
    const int k = blockIdx.x, lane = threadIdx.x;
    float4 v = *(const float4*)(Cg + (size_t)k * ND + lane * 4);
    float s = v.x * v.x + v.y * v.y + v.z * v.z + v.w * v.w;
#pragma unroll
    for (int m = 1; m <= 32; m <<= 1) s += __shfl_xor(s, m, 64);
    if (lane == 0) csq[k] = s;
    u16x4 h;
    h[0] = __builtin_bit_cast(unsigned short, (_Float16)v.x);
    h[1] = __builtin_bit_cast(unsigned short, (_Float16)v.y);
    h[2] = __builtin_bit_cast(unsigned short, (_Float16)v.z);
    h[3] = __builtin_bit_cast(unsigned short, (_Float16)v.w);
    const int colblk = k >> 7, col = k & 127;
    const size_t idx = ((size_t)colblk << 15) + ((((size_t)(lane >> 1) << 7) + col) << 3) + ((lane & 1) << 2);
    *(u16x4*)(Cf + idx) = h;
}

// ---- macros for the pipelined main loop (static indices via _Pragma unroll) ----
#define LOADHALF(OFF)                                                     \
    {                                                                     \
        _Pragma("unroll") for (int q = 0; q < 4; ++q) {                   \
            w[q * 2]         = *(const float4*)(a0 + (OFF) + q * 32);     \
            w[q * 2 + 1]     = *(const float4*)(a0 + (OFF) + q * 32 + 4); \
            w[8 + q * 2]     = *(const float4*)(a1 + (OFF) + q * 32);     \
            w[8 + q * 2 + 1] = *(const float4*)(a1 + (OFF) + q * 32 + 4); \
        }                                                                 \
    }

#define CVTHALF(BASE)                                                                \
    {                                                                                \
        _Pragma("unroll") for (int m = 0; m < 2; ++m) {                              \
            _Pragma("unroll") for (int q = 0; q < 4; ++q) {                          \
                float4 v0 = w[m * 8 + q * 2], v1 = w[m * 8 + q * 2 + 1];             \
                if (colblk == 0)                                                     \
                    e2 += v0.x * v0.x + v0.y * v0.y + v0.z * v0.z + v0.w * v0.w +    \
                          v1.x * v1.x + v1.y * v1.y + v1.z * v1.z + v1.w * v1.w;     \
                u16x8 h;                                                             \
                h[0] = __builtin_bit_cast(unsigned short, (_Float16)v0.x);           \
                h[1] = __builtin_bit_cast(unsigned short, (_Float16)v0.y);           \
                h[2] = __builtin_bit_cast(unsigned short, (_Float16)v0.z);           \
                h[3] = __builtin_bit_cast(unsigned short, (_Float16)v0.w);           \
                h[4] = __builtin_bit_cast(unsigned short, (_Float16)v1.x);           \
                h[5] = __builtin_bit_cast(unsigned short, (_Float16)v1.y);           \
                h[6] = __builtin_bit_cast(unsigned short, (_Float16)v1.z);           \
                h[7] = __builtin_bit_cast(unsigned short, (_Float16)v1.w);           \
                A[m][(BASE) + q] = __builtin_bit_cast(f16x8, h);                     \
            }                                                                        \
        }                                                                            \
    }

#define COMPUTE4(KS0)                                                                          \
    {                                                                                          \
        _Pragma("unroll") for (int kq = 0; kq < 4; ++kq) {                                     \
            const int ks = (KS0) + kq;                                                         \
            u16x8 bf[8];                                                                       \
            _Pragma("unroll") for (int n = 0; n < 8; ++n)                                      \
                bf[n] = *(const u16x8*)&Blds[((((ks << 2) + l4) << 7) + n * 16 + l15) << 3];   \
            _Pragma("unroll") for (int m = 0; m < 2; ++m)                                      \
                _Pragma("unroll") for (int n = 0; n < 8; ++n)                                  \
                    acc[m][n] = __builtin_amdgcn_mfma_f32_16x16x32_f16(                        \
                        A[m][ks], __builtin_bit_cast(f16x8, bf[n]), acc[m][n], 0, 0, 0);       \
        }                                                                                      \
    }

// ---------------- main: persistent blocks, cross-rowtile prefetch pipeline ----
// grid 512 = 128 rowgroups(1024 rows) x 4 colblks(128 cols). 2 blocks/CU, all
// resident. The 4 colblk-mates of a rowgroup land on one XCD (u = xcd*64+slot).
// Per block: stage B once; sweep 8 rowtiles with half-depth A prefetch so every
// wave keeps loads in flight continuously (MLP fix for the 0.5 TB/s plateau).
__global__ __launch_bounds__(256, 2) void kmeans_mfma(
    const float* __restrict__ E, const unsigned short* __restrict__ Cf,
    const float* __restrict__ csq, u64* __restrict__ partials,
    float* __restrict__ e2s) {
    __shared__ unsigned short Blds[32768];  // 64 KB

    const int tid = threadIdx.x;
    const int xcd = blockIdx.x & 7, slot = blockIdx.x >> 3;
    const int u = xcd * 64 + slot;  // unit id: rowgroup-mates share an XCD
    const int rowgroup = u >> 2, colblk = u & 3;
    const int colbase = colblk << 7;

    const int lane = tid & 63, wid = tid >> 6;
    const int l15 = lane & 15, l4 = lane >> 4;

    // ---- stage B panel (linear 64 KB copy) ----
    const unsigned short* CfB = Cf + ((size_t)colblk << 15);
#pragma unroll
    for (int i = 0; i < 16; ++i) {
        const int g = tid + i * 256;
        *(u16x8*)&Blds[g << 3] = *(const u16x8*)(CfB + ((size_t)g << 3));
    }

    // ---- csq fragment (col = colbase + n*16 + l15) ----
    float cs[8];
#pragma unroll
    for (int n = 0; n < 8; ++n) cs[n] = csq[colbase + n * 16 + l15];

    // ---- A pointers: 2 rows per thread, advance 128 rows (32768 floats)/rowtile
    const int wrow0 = (rowgroup << 10) + wid * 32;
    const float* a0 = E + (size_t)(wrow0 + l15) * ND + l4 * 8;
    const float* a1 = E + (size_t)(wrow0 + 16 + l15) * ND + l4 * 8;

    f16x8 A[2][8];   // current rowtile, fp16 (64 VGPR)
    float4 w[16];    // in-flight half-rowtile fp32 (64 VGPR)
    float e2 = 0.f;

    // ---- prologue: rowtile 0 (both halves, serial) ----
    LOADHALF(0);
    CVTHALF(0);
    LOADHALF(128);
    CVTHALF(4);
    __syncthreads();  // B panel ready

    // ---- persistent sweep over 8 rowtiles ----
#pragma unroll 1
    for (int i = 0; i < 8; ++i) {
        f32x4 acc[2][8] = {};
        const int nextoff = (i + 1) << 15;
        if (i < 7) LOADHALF(nextoff);          // next lo in flight under ks0-3
        COMPUTE4(0);
        if (i < 7) {
            CVTHALF(0);                        // next lo -> A[0..3] (consumed)
            LOADHALF(nextoff + 128);           // next hi in flight under ks4-7
        }
        COMPUTE4(4);
        if (i < 7) CVTHALF(4);                 // next hi -> A[4..7]

        // ---- epilogue rowtile i: packed-u64 top-2 over 128 cols ----
#pragma unroll
        for (int m = 0; m < 2; ++m) {
#pragma unroll
            for (int j = 0; j < 4; ++j) {
                u64 k1 = 0, k2 = 0;  // 0 == -inf sentinel (scores finite)
#pragma unroll
                for (int n = 0; n < 8; ++n) {
                    const int col = colbase + n * 16 + l15;
                    const float s = cs[n] - 2.0f * acc[m][n][j];
                    const unsigned b = __builtin_bit_cast(unsigned, s);
                    const unsigned mono = (s < 0.f) ? ~b : (b | 0x80000000u);
                    const u64 key = ((u64)mono << 32) | (unsigned)(NK - 1 - col);
                    const u64 mn = k1 < key ? k1 : key;
                    k1 = k1 < key ? key : k1;
                    k2 = k2 < mn ? mn : k2;
                }
#pragma unroll
                for (int mk = 1; mk <= 8; mk <<= 1) {
                    const u64 o1 = __shfl_xor(k1, mk, 64);
                    const u64 o2 = __shfl_xor(k2, mk, 64);
                    const u64 mn = k1 < o1 ? k1 : o1;
                    k1 = k1 < o1 ? o1 : k1;
                    const u64 mx2 = k2 < o2 ? o2 : k2;
                    k2 = mn < mx2 ? mx2 : mn;
                }
                if (l15 == 0) {
                    const int row = wrow0 + (i << 7) + m * 16 + l4 * 4 + j;
                    ulonglong2 o;
                    o.x = k1; o.y = k2;
                    *(ulonglong2*)&partials[((size_t)row << 3) + colblk * 2] = o;
                }
            }
        }
    }

    if (colblk == 0) {
#pragma unroll
        for (int mk = 1; mk <= 32; mk <<= 1) e2 += __shfl_xor(e2, mk, 64);
        if (lane == 0) e2s[rowgroup * 4 + wid] = e2;
    }
}

// ---------------- combine: merge 4 packed top-2s, rescore near-ties ----------------
__global__ __launch_bounds__(256) void combine_kernel(
    const u64* __restrict__ partials, const float* __restrict__ csq,
    const float* __restrict__ E, const float* __restrict__ Cg,
    float* __restrict__ out, float* __restrict__ sum2) {
    const int n = blockIdx.x * 256 + threadIdx.x;
    const ulonglong2* p = (const ulonglong2*)(partials + ((size_t)n << 3));
    ulonglong2 a = p[0];
    u64 k1 = a.x, k2 = a.y;
#pragma unroll
    for (int cb = 1; cb < 4; ++cb) {
        ulonglong2 b = p[cb];
        const u64 mn = k1 < b.x ? k1 : b.x;
        k1 = k1 < b.x ? b.x : k1;
        const u64 mx2 = k2 < b.y ? b.y : k2;
        k2 = mn < mx2 ? mx2 : mn;
    }
    const unsigned hi1 = (unsigned)(k1 >> 32);
    float v1 = __builtin_bit_cast(float, (hi1 & 0x80000000u) ? (hi1 ^ 0x80000000u) : ~hi1);
    int i1 = NK - 1 - (int)(unsigned)(k1 & 0xFFFFFFFFull);
    const unsigned hi2 = (unsigned)(k2 >> 32);
    const float v2 = __builtin_bit_cast(float, (hi2 & 0x80000000u) ? (hi2 ^ 0x80000000u) : ~hi2);
    const int i2 = NK - 1 - (int)(unsigned)(k2 & 0xFFFFFFFFull);

    if (v1 - v2 <= DELTA) {  // near-tie: exact fp32 rescore of both candidates
        const float* e = E + (size_t)n * ND;
        const float* c1p = Cg + (size_t)i1 * ND;
        const float* c2p = Cg + (size_t)i2 * ND;
        float d1 = 0.f, d2 = 0.f;
        for (int d = 0; d < ND; d += 4) {
            float4 ev = *(const float4*)(e + d);
            float4 cv1 = *(const float4*)(c1p + d);
            float4 cv2 = *(const float4*)(c2p + d);
            d1 += ev.x * cv1.x + ev.y * cv1.y + ev.z * cv1.z + ev.w * cv1.w;
            d2 += ev.x * cv2.x + ev.y * cv2.y + ev.z * cv2.z + ev.w * cv2.w;
        }
        const float s1 = csq[i1] - 2.f * d1;
        const float s2 = csq[i2] - 2.f * d2;
        if (s2 > s1 || (s2 == s1 && i2 < i1)) { v1 = s2; i1 = i2; } else { v1 = s1; }
    }
    out[1 + n] = (float)i1;
    float s = v1;
#pragma unroll
    for (int mk = 1; mk <= 32; mk <<= 1) s += __shfl_xor(s, mk, 64);
    __shared__ float wsm[4];
    const int lane = threadIdx.x & 63, wd = threadIdx.x >> 6;
    if (lane == 0) wsm[wd] = s;
    __syncthreads();
    if (threadIdx.x == 0) sum2[blockIdx.x] = wsm[0] + wsm[1] + wsm[2] + wsm[3];
}

// ---------------- final: loss = lambda^2 * (sum e^2 + sum row maxima) ----------------
__global__ __launch_bounds__(256) void final_kernel(const float* __restrict__ e2s,
                                                    const float* __restrict__ sum2,
                                                    float* __restrict__ out) {
    float s = 0.f;
    for (int i = threadIdx.x; i < 512; i += 256) s += e2s[i];
    for (int i = threadIdx.x; i < 512; i += 256) s += sum2[i];
#pragma unroll
    for (int mk = 1; mk <= 32; mk <<= 1) s += __shfl_xor(s, mk, 64);
    __shared__ float wsm[4];
    const int lane = threadIdx.x & 63, wd = threadIdx.x >> 6;
    if (lane == 0) wsm[wd] = s;
    __syncthreads();
    if (threadIdx.x == 0) out[0] = LM2 * (wsm[0] + wsm[1] + wsm[2] + wsm[3]);
}

extern "C" void kernel_launch(void* const* d_in, const int* in_sizes, int n_in,
                              void* d_out, int out_size, void* d_ws, size_t ws_size,
                              hipStream_t stream) {
    (void)n_in; (void)out_size; (void)ws_size;
    const float* E = (const float*)d_in[0];
    const float* Cg = (const float*)d_in[1];
    float* out = (float*)d_out;

    // ws (floats): csq[512] | e2s[512] | sum2[512] | pad[1536] | Cf16 (256KB) | partials (8MB u64)
    float* wsf = (float*)d_ws;
    float* csq = wsf;
    float* e2s = wsf + 512;
    float* sum2 = wsf + 1024;
    unsigned short* Cf = (unsigned short*)(wsf + 3072);
    u64* partials = (u64*)(wsf + 3072 + 65536);

    const int N = in_sizes[0] / ND;  // 131072

    prep_kernel<<<NK, 64, 0, stream>>>(Cg, csq, Cf);
    kmeans_mfma<<<512, 256, 0, stream>>>(E, Cf, csq, partials, e2s);
    combine_kernel<<<N / 256, 256, 0, stream>>>(partials, csq, E, Cg, out, sum2);
    final_kernel<<<1, 256, 0, stream>>>(e2s, sum2, out);
}

// Round 8
// 142.123 us; speedup vs baseline: 3.0881x; 3.0881x over previous
//
#include <hip/hip_runtime.h>

#define ND 256       // embedding dim
#define NK 512       // centroids
#define LM2 0.0625f  // lambda^2
#define DELTA 0.25f  // approx top-2 gap below this -> exact fp32 rescore

typedef _Float16 f16x8 __attribute__((ext_vector_type(8)));
typedef float f32x4 __attribute__((ext_vector_type(4)));
typedef unsigned short u16x8 __attribute__((ext_vector_type(8)));
typedef unsigned short u16x4 __attribute__((ext_vector_type(4)));
typedef unsigned long long u64;

static __device__ __forceinline__ u64 umax64(u64 a, u64 b) { return a < b ? b : a; }
static __device__ __forceinline__ u64 umin64(u64 a, u64 b) { return a < b ? a : b; }

// ---------------- prep: csq[k] + fp16 centroids in per-64col-panel frag order --
// Cf halves layout: [panel 8][krow 32][col 64][8], krow = (d>>5)*4 + ((d>>3)&3).
// A 16B granule = one lane's B-frag slice -> main reads frags conflict-free
// (same granule scheme as r4-r6: measured 0 bank conflicts).
__global__ __launch_bounds__(64) void prep_kernel(const float* __restrict__ Cg,
                                                  float* __restrict__ csq,
                                                  unsigned short* __restrict__ Cf) {
    const int k = blockIdx.x, lane = threadIdx.x;
    float4 v = *(const float4*)(Cg + (size_t)k * ND + lane * 4);
    float s = v.x * v.x + v.y * v.y + v.z * v.z + v.w * v.w;
#pragma unroll
    for (int m = 1; m <= 32; m <<= 1) s += __shfl_xor(s, m, 64);
    if (lane == 0) csq[k] = s;
    u16x4 h;
    h[0] = __builtin_bit_cast(unsigned short, (_Float16)v.x);
    h[1] = __builtin_bit_cast(unsigned short, (_Float16)v.y);
    h[2] = __builtin_bit_cast(unsigned short, (_Float16)v.z);
    h[3] = __builtin_bit_cast(unsigned short, (_Float16)v.w);
    const int panel = k >> 6, col = k & 63;
    const int krow = (lane >> 3) * 4 + ((lane >> 1) & 3);  // d0 = lane*4
    const size_t idx = ((size_t)panel << 14) + ((((size_t)krow << 6) + col) << 3) + ((lane & 1) << 2);
    *(u16x4*)(Cf + idx) = h;
}

// ---------------- main: 128 rows/block, full-N sweep over 8 async B panels ----
// grid 1024 (one block per 128 rows -> E read from HBM exactly once).
// block: 4 waves x 32 rows; A in regs (fp16, 64 VGPR); B panels (64 cols,
// 32 KB) double-buffered in LDS: issue next-panel loads BEFORE computing the
// current panel (T14), ds_write after, ONE barrier per panel. Running per-lane
// u64 top-2 keys across panels; single shfl merge at block end.
__global__ __launch_bounds__(256, 2) void kmeans_mfma(
    const float* __restrict__ E, const unsigned short* __restrict__ Cf,
    const float* __restrict__ csq, u64* __restrict__ partials,
    float* __restrict__ e2s) {
    __shared__ unsigned short Bbuf[2][16384];  // 2 x 32 KB

    const int tid = threadIdx.x;
    const int lane = tid & 63, wid = tid >> 6;
    const int l15 = lane & 15, l4 = lane >> 4;
    const int rowbase = blockIdx.x << 7;
    const int wrow = rowbase + wid * 32;

    // ---- A stage (r6-proven pattern): 2 rows/thread, frag-sliced loads ----
    const float* a0 = E + (size_t)(wrow + l15) * ND + l4 * 8;
    const float* a1 = E + (size_t)(wrow + 16 + l15) * ND + l4 * 8;

    f16x8 A[2][8];  // [m][ks]
    float e2 = 0.f;
#pragma unroll
    for (int m = 0; m < 2; ++m) {
        const float* ap = m ? a1 : a0;
        float4 t0[8], t1[8];
#pragma unroll
        for (int ks = 0; ks < 8; ++ks) {
            t0[ks] = *(const float4*)(ap + ks * 32);
            t1[ks] = *(const float4*)(ap + ks * 32 + 4);
        }
#pragma unroll
        for (int ks = 0; ks < 8; ++ks) {
            float4 v0 = t0[ks], v1 = t1[ks];
            e2 += v0.x * v0.x + v0.y * v0.y + v0.z * v0.z + v0.w * v0.w +
                  v1.x * v1.x + v1.y * v1.y + v1.z * v1.z + v1.w * v1.w;
            u16x8 h;
            h[0] = __builtin_bit_cast(unsigned short, (_Float16)v0.x);
            h[1] = __builtin_bit_cast(unsigned short, (_Float16)v0.y);
            h[2] = __builtin_bit_cast(unsigned short, (_Float16)v0.z);
            h[3] = __builtin_bit_cast(unsigned short, (_Float16)v0.w);
            h[4] = __builtin_bit_cast(unsigned short, (_Float16)v1.x);
            h[5] = __builtin_bit_cast(unsigned short, (_Float16)v1.y);
            h[6] = __builtin_bit_cast(unsigned short, (_Float16)v1.z);
            h[7] = __builtin_bit_cast(unsigned short, (_Float16)v1.w);
            A[m][ks] = __builtin_bit_cast(f16x8, h);
        }
    }

    // ---- stage panel 0 into Bbuf[0] ----
    {
        u16x8 r[8];
#pragma unroll
        for (int i = 0; i < 8; ++i)
            r[i] = *(const u16x8*)(Cf + ((size_t)(tid + i * 256) << 3));
#pragma unroll
        for (int i = 0; i < 8; ++i)
            *(u16x8*)&Bbuf[0][(size_t)(tid + i * 256) << 3] = r[i];
    }
    __syncthreads();

    u64 k12[2][4][2];
#pragma unroll
    for (int m = 0; m < 2; ++m)
#pragma unroll
        for (int j = 0; j < 4; ++j) { k12[m][j][0] = 0; k12[m][j][1] = 0; }

    const unsigned short* cur = Bbuf[0];
    unsigned short* nxt = (unsigned short*)Bbuf[1];

#pragma unroll 1
    for (int p = 0; p < 8; ++p) {
        // issue next panel's global loads FIRST (latency hides under compute)
        u16x8 breg[8];
        if (p < 7) {
            const unsigned short* src = Cf + ((size_t)(p + 1) << 14);
#pragma unroll
            for (int i = 0; i < 8; ++i)
                breg[i] = *(const u16x8*)(src + ((size_t)(tid + i * 256) << 3));
        }
        float csp[4];
        unsigned ck[4];
#pragma unroll
        for (int n = 0; n < 4; ++n) {
            const int col = (p << 6) + n * 16 + l15;
            csp[n] = csq[col];
            ck[n] = (unsigned)(NK - 1 - col);
        }
        // compute current panel: 8 ks x {4 B-frag ds_read_b128, 8 MFMA}
        f32x4 acc[2][4] = {};
#pragma unroll
        for (int ks = 0; ks < 8; ++ks) {
            u16x8 bf[4];
#pragma unroll
            for (int n = 0; n < 4; ++n)
                bf[n] = *(const u16x8*)&cur[(size_t)((((ks << 2) + l4) << 6) + n * 16 + l15) << 3];
#pragma unroll
            for (int m = 0; m < 2; ++m)
#pragma unroll
                for (int n = 0; n < 4; ++n)
                    acc[m][n] = __builtin_amdgcn_mfma_f32_16x16x32_f16(
                        A[m][ks], __builtin_bit_cast(f16x8, bf[n]), acc[m][n], 0, 0, 0);
        }
        // fold this panel into the running per-lane top-2 (no shfl here)
#pragma unroll
        for (int m = 0; m < 2; ++m)
#pragma unroll
            for (int j = 0; j < 4; ++j)
#pragma unroll
                for (int n = 0; n < 4; ++n) {
                    const float s = fmaf(-2.f, acc[m][n][j], csp[n]);
                    const unsigned b = __builtin_bit_cast(unsigned, s);
                    const unsigned mono = (s < 0.f) ? ~b : (b | 0x80000000u);
                    const u64 key = ((u64)mono << 32) | ck[n];
                    const u64 mn = umin64(k12[m][j][0], key);
                    k12[m][j][0] = umax64(k12[m][j][0], key);
                    k12[m][j][1] = umax64(k12[m][j][1], mn);
                }
        // write next panel into the other buffer; one barrier per panel
        if (p < 7) {
#pragma unroll
            for (int i = 0; i < 8; ++i)
                *(u16x8*)&nxt[(size_t)(tid + i * 256) << 3] = breg[i];
            __syncthreads();
            unsigned short* t = (unsigned short*)cur;
            cur = nxt;
            nxt = t;
        }
    }

    // ---- single end-of-block merge across the 16 l15 lanes ----
#pragma unroll
    for (int m = 0; m < 2; ++m)
#pragma unroll
        for (int j = 0; j < 4; ++j) {
            u64 k1 = k12[m][j][0], k2 = k12[m][j][1];
#pragma unroll
            for (int mk = 1; mk <= 8; mk <<= 1) {
                const u64 o1 = __shfl_xor(k1, mk, 64);
                const u64 o2 = __shfl_xor(k2, mk, 64);
                const u64 mn = umin64(k1, o1);
                k1 = umax64(k1, o1);
                k2 = umax64(umax64(k2, o2), mn);
            }
            if (l15 == 0) {
                const int row = wrow + m * 16 + l4 * 4 + j;
                ulonglong2 o;
                o.x = k1;
                o.y = k2;
                *(ulonglong2*)&partials[(size_t)row * 2] = o;
            }
        }

    // ---- e2 partial (each row counted exactly once chip-wide) ----
#pragma unroll
    for (int mk = 1; mk <= 32; mk <<= 1) e2 += __shfl_xor(e2, mk, 64);
    if (lane == 0) e2s[blockIdx.x * 4 + wid] = e2;
}

// ---------------- combine: decode top-2, rescore near-ties, write assign ----
__global__ __launch_bounds__(256) void combine_kernel(
    const u64* __restrict__ partials, const float* __restrict__ csq,
    const float* __restrict__ E, const float* __restrict__ Cg,
    float* __restrict__ out, float* __restrict__ sum2) {
    const int n = blockIdx.x * 256 + threadIdx.x;
    const ulonglong2 a = *(const ulonglong2*)&partials[(size_t)n * 2];
    const u64 k1 = a.x, k2 = a.y;
    const unsigned hi1 = (unsigned)(k1 >> 32);
    float v1 = __builtin_bit_cast(float, (hi1 & 0x80000000u) ? (hi1 ^ 0x80000000u) : ~hi1);
    int i1 = NK - 1 - (int)(unsigned)(k1 & 0xFFFFFFFFull);
    const unsigned hi2 = (unsigned)(k2 >> 32);
    const float v2 = __builtin_bit_cast(float, (hi2 & 0x80000000u) ? (hi2 ^ 0x80000000u) : ~hi2);
    const int i2 = NK - 1 - (int)(unsigned)(k2 & 0xFFFFFFFFull);

    if (v1 - v2 <= DELTA) {  // near-tie: exact fp32 rescore of both candidates
        const float* e = E + (size_t)n * ND;
        const float* c1p = Cg + (size_t)i1 * ND;
        const float* c2p = Cg + (size_t)i2 * ND;
        float d1 = 0.f, d2 = 0.f;
        for (int d = 0; d < ND; d += 4) {
            float4 ev = *(const float4*)(e + d);
            float4 cv1 = *(const float4*)(c1p + d);
            float4 cv2 = *(const float4*)(c2p + d);
            d1 += ev.x * cv1.x + ev.y * cv1.y + ev.z * cv1.z + ev.w * cv1.w;
            d2 += ev.x * cv2.x + ev.y * cv2.y + ev.z * cv2.z + ev.w * cv2.w;
        }
        const float s1 = csq[i1] - 2.f * d1;
        const float s2 = csq[i2] - 2.f * d2;
        if (s2 > s1 || (s2 == s1 && i2 < i1)) { v1 = s2; i1 = i2; } else { v1 = s1; }
    }
    out[1 + n] = (float)i1;
    float s = v1;
#pragma unroll
    for (int mk = 1; mk <= 32; mk <<= 1) s += __shfl_xor(s, mk, 64);
    __shared__ float wsm[4];
    const int lane = threadIdx.x & 63, wd = threadIdx.x >> 6;
    if (lane == 0) wsm[wd] = s;
    __syncthreads();
    if (threadIdx.x == 0) sum2[blockIdx.x] = wsm[0] + wsm[1] + wsm[2] + wsm[3];
}

// ---------------- final: loss = lambda^2 * (sum e^2 + sum row maxima) --------
__global__ __launch_bounds__(256) void final_kernel(const float* __restrict__ e2s,
                                                    const float* __restrict__ sum2,
                                                    float* __restrict__ out) {
    float s = 0.f;
    for (int i = threadIdx.x; i < 4096; i += 256) s += e2s[i];
    for (int i = threadIdx.x; i < 512; i += 256) s += sum2[i];
#pragma unroll
    for (int mk = 1; mk <= 32; mk <<= 1) s += __shfl_xor(s, mk, 64);
    __shared__ float wsm[4];
    const int lane = threadIdx.x & 63, wd = threadIdx.x >> 6;
    if (lane == 0) wsm[wd] = s;
    __syncthreads();
    if (threadIdx.x == 0) out[0] = LM2 * (wsm[0] + wsm[1] + wsm[2] + wsm[3]);
}

extern "C" void kernel_launch(void* const* d_in, const int* in_sizes, int n_in,
                              void* d_out, int out_size, void* d_ws, size_t ws_size,
                              hipStream_t stream) {
    (void)n_in; (void)out_size; (void)ws_size;
    const float* E = (const float*)d_in[0];
    const float* Cg = (const float*)d_in[1];
    float* out = (float*)d_out;

    // ws (floats): csq[512] | e2s[4096] | sum2[512] | Cf16 (256KB = 65536 f) | partials (2MB)
    float* wsf = (float*)d_ws;
    float* csq = wsf;
    float* e2s = wsf + 512;
    float* sum2 = wsf + 4608;
    unsigned short* Cf = (unsigned short*)(wsf + 5120);
    u64* partials = (u64*)(wsf + 5120 + 65536);

    const int N = in_sizes[0] / ND;  // 131072
    const int nblk = N >> 7;         // 1024

    prep_kernel<<<NK, 64, 0, stream>>>(Cg, csq, Cf);
    kmeans_mfma<<<nblk, 256, 0, stream>>>(E, Cf, csq, partials, e2s);
    combine_kernel<<<N / 256, 256, 0, stream>>>(partials, csq, E, Cg, out, sum2);
    final_kernel<<<1, 256, 0, stream>>>(e2s, sum2, out);
}

// Round 9
// 108.611 us; speedup vs baseline: 4.0410x; 1.3086x over previous
//
#include <hip/hip_runtime.h>

#define ND 256       // embedding dim
#define NK 512       // centroids
#define LM2 0.0625f  // lambda^2
#define DELTA 0.25f  // approx top-2 gap below this -> exact fp32 rescore

typedef _Float16 f16x8 __attribute__((ext_vector_type(8)));
typedef float f32x4 __attribute__((ext_vector_type(4)));
typedef unsigned short u16x8 __attribute__((ext_vector_type(8)));
typedef unsigned short u16x4 __attribute__((ext_vector_type(4)));

// async 16B global->LDS (zero VGPR staging). LDS dest is wave-uniform base;
// HW adds lane*16. Global src is per-lane.
#define GLD16(GSRC, LDST)                                                      \
    __builtin_amdgcn_global_load_lds(                                         \
        (const __attribute__((address_space(1))) void*)(GSRC),                \
        (__attribute__((address_space(3))) void*)(LDST), 16, 0, 0)

// ---------------- prep: csq[k] + fp16 centroids in per-64col-panel frag order --
// Cf layout: [panel 8][krow 32][col 64][8], krow = (d>>5)*4 + ((d>>3)&3).
// 16B granule = one lane's B-frag slice (measured 0 bank conflicts r4-r8).
__global__ __launch_bounds__(64) void prep_kernel(const float* __restrict__ Cg,
                                                  float* __restrict__ csq,
                                                  unsigned short* __restrict__ Cf) {
    const int k = blockIdx.x, lane = threadIdx.x;
    float4 v = *(const float4*)(Cg + (size_t)k * ND + lane * 4);
    float s = v.x * v.x + v.y * v.y + v.z * v.z + v.w * v.w;
#pragma unroll
    for (int m = 1; m <= 32; m <<= 1) s += __shfl_xor(s, m, 64);
    if (lane == 0) csq[k] = s;
    u16x4 h;
    h[0] = __builtin_bit_cast(unsigned short, (_Float16)v.x);
    h[1] = __builtin_bit_cast(unsigned short, (_Float16)v.y);
    h[2] = __builtin_bit_cast(unsigned short, (_Float16)v.z);
    h[3] = __builtin_bit_cast(unsigned short, (_Float16)v.w);
    const int panel = k >> 6, col = k & 63;
    const int krow = (lane >> 3) * 4 + ((lane >> 1) & 3);  // d0 = lane*4
    const size_t idx = ((size_t)panel << 14) + ((((size_t)krow << 6) + col) << 3) + ((lane & 1) << 2);
    *(u16x4*)(Cf + idx) = h;
}

// ---------------- main: 128 rows/block, full-N sweep, gload_lds B panels ----
// grid 1024: E read from HBM exactly once; A in regs (fp16, 64 VGPR, r6-proven
// no-spill staging); B panels (64 cols, 32 KB) double-buffered via
// global_load_lds (ZERO staging registers), ONE barrier per panel (its vmcnt
// drain = completion wait; loads get a full compute phase to land). Running
// per-lane u32 top-2 keys; single shfl merge at block end.
__global__ __launch_bounds__(256, 2) void kmeans_mfma(
    const float* __restrict__ E, const unsigned short* __restrict__ Cf,
    const float* __restrict__ csq, uint2* __restrict__ partials,
    float* __restrict__ e2s) {
    __shared__ unsigned short Bbuf[2][16384];  // 2 x 32 KB

    const int tid = threadIdx.x;
    const int lane = tid & 63, wid = tid >> 6;
    const int l15 = lane & 15, l4 = lane >> 4;
    const int rowbase = blockIdx.x << 7;
    const int wrow = rowbase + wid * 32;

    // ---- issue panel 0 staging (flies during A-stage) ----
    {
        const unsigned short* gsrc = Cf;
#pragma unroll
        for (int i = 0; i < 8; ++i)
            GLD16(gsrc + (((size_t)(wid * 8 + i) * 64 + lane) << 3),
                  &Bbuf[0][(size_t)(wid * 8 + i) << 9]);
    }

    // ---- A stage (r6-proven): 2 rows/thread, frag-sliced loads, cvt to fp16 --
    const float* a0 = E + (size_t)(wrow + l15) * ND + l4 * 8;
    const float* a1 = E + (size_t)(wrow + 16 + l15) * ND + l4 * 8;

    f16x8 A[2][8];  // [m][ks]
    float e2 = 0.f;
#pragma unroll
    for (int m = 0; m < 2; ++m) {
        const float* ap = m ? a1 : a0;
        float4 t0[8], t1[8];
#pragma unroll
        for (int ks = 0; ks < 8; ++ks) {
            t0[ks] = *(const float4*)(ap + ks * 32);
            t1[ks] = *(const float4*)(ap + ks * 32 + 4);
        }
#pragma unroll
        for (int ks = 0; ks < 8; ++ks) {
            float4 v0 = t0[ks], v1 = t1[ks];
            e2 += v0.x * v0.x + v0.y * v0.y + v0.z * v0.z + v0.w * v0.w +
                  v1.x * v1.x + v1.y * v1.y + v1.z * v1.z + v1.w * v1.w;
            u16x8 h;
            h[0] = __builtin_bit_cast(unsigned short, (_Float16)v0.x);
            h[1] = __builtin_bit_cast(unsigned short, (_Float16)v0.y);
            h[2] = __builtin_bit_cast(unsigned short, (_Float16)v0.z);
            h[3] = __builtin_bit_cast(unsigned short, (_Float16)v0.w);
            h[4] = __builtin_bit_cast(unsigned short, (_Float16)v1.x);
            h[5] = __builtin_bit_cast(unsigned short, (_Float16)v1.y);
            h[6] = __builtin_bit_cast(unsigned short, (_Float16)v1.z);
            h[7] = __builtin_bit_cast(unsigned short, (_Float16)v1.w);
            A[m][ks] = __builtin_bit_cast(f16x8, h);
        }
    }

    unsigned k1[2][4], k2[2][4];
#pragma unroll
    for (int m = 0; m < 2; ++m)
#pragma unroll
        for (int j = 0; j < 4; ++j) { k1[m][j] = 0u; k2[m][j] = 0u; }

#pragma unroll 1
    for (int p = 0; p < 8; ++p) {
        __syncthreads();  // drains vmcnt: panel p staged; frees buf[(p+1)&1]
        if (p < 7) {      // issue next panel (lands during this panel's compute)
            const unsigned short* gsrc = Cf + ((size_t)(p + 1) << 14);
            unsigned short* ldst = (unsigned short*)Bbuf[(p + 1) & 1];
#pragma unroll
            for (int i = 0; i < 8; ++i)
                GLD16(gsrc + (((size_t)(wid * 8 + i) * 64 + lane) << 3),
                      &ldst[(size_t)(wid * 8 + i) << 9]);
        }
        float csp[4];
        unsigned ck[4];
#pragma unroll
        for (int n = 0; n < 4; ++n) {
            const int col = (p << 6) + n * 16 + l15;
            csp[n] = csq[col];
            ck[n] = (unsigned)(NK - 1 - col);
        }
        // compute current panel: 8 ks x {4 B-frag ds_read_b128, 8 MFMA}
        const unsigned short* cur = Bbuf[p & 1];
        f32x4 acc[2][4] = {};
#pragma unroll
        for (int ks = 0; ks < 8; ++ks) {
            u16x8 bf[4];
#pragma unroll
            for (int n = 0; n < 4; ++n)
                bf[n] = *(const u16x8*)&cur[(size_t)((((ks << 2) + l4) << 6) + n * 16 + l15) << 3];
#pragma unroll
            for (int m = 0; m < 2; ++m)
#pragma unroll
                for (int n = 0; n < 4; ++n)
                    acc[m][n] = __builtin_amdgcn_mfma_f32_16x16x32_f16(
                        A[m][ks], __builtin_bit_cast(f16x8, bf[n]), acc[m][n], 0, 0, 0);
        }
        // fold panel into running per-lane u32 top-2 keys
        // key = mono(score) with low 9 bits = 511-col (chop err ~5e-3 << DELTA)
#pragma unroll
        for (int m = 0; m < 2; ++m)
#pragma unroll
            for (int j = 0; j < 4; ++j)
#pragma unroll
                for (int n = 0; n < 4; ++n) {
                    const float s = fmaf(-2.f, acc[m][n][j], csp[n]);
                    const unsigned b = __builtin_bit_cast(unsigned, s);
                    const unsigned mono = b ^ ((unsigned)((int)b >> 31) | 0x80000000u);
                    const unsigned key = (mono & 0xFFFFFE00u) | ck[n];
                    const unsigned mn = min(k1[m][j], key);
                    k1[m][j] = max(k1[m][j], key);
                    k2[m][j] = max(k2[m][j], mn);
                }
    }

    // ---- single end-of-block merge across the 16 l15 lanes ----
#pragma unroll
    for (int m = 0; m < 2; ++m)
#pragma unroll
        for (int j = 0; j < 4; ++j) {
            unsigned a = k1[m][j], b2 = k2[m][j];
#pragma unroll
            for (int mk = 1; mk <= 8; mk <<= 1) {
                const unsigned oa = __shfl_xor(a, mk, 64);
                const unsigned ob = __shfl_xor(b2, mk, 64);
                const unsigned mn = min(a, oa);
                a = max(a, oa);
                b2 = max(max(b2, ob), mn);
            }
            if (l15 == 0) {
                const int row = wrow + m * 16 + l4 * 4 + j;
                uint2 o;
                o.x = a;
                o.y = b2;
                partials[row] = o;
            }
        }

    // ---- e2 partial (each row counted exactly once chip-wide) ----
#pragma unroll
    for (int mk = 1; mk <= 32; mk <<= 1) e2 += __shfl_xor(e2, mk, 64);
    if (lane == 0) e2s[blockIdx.x * 4 + wid] = e2;
}

// ---------------- combine: decode top-2 keys, rescore near-ties --------------
__global__ __launch_bounds__(256) void combine_kernel(
    const uint2* __restrict__ partials, const float* __restrict__ csq,
    const float* __restrict__ E, const float* __restrict__ Cg,
    float* __restrict__ out, float* __restrict__ sum2) {
    const int n = blockIdx.x * 256 + threadIdx.x;
    const uint2 kk = partials[n];
    const unsigned m1 = kk.x & 0xFFFFFE00u;
    float v1 = __builtin_bit_cast(float, (m1 & 0x80000000u) ? (m1 ^ 0x80000000u) : ~m1);
    int i1 = (int)(NK - 1) - (int)(kk.x & 511u);
    const unsigned m2 = kk.y & 0xFFFFFE00u;
    const float v2 = __builtin_bit_cast(float, (m2 & 0x80000000u) ? (m2 ^ 0x80000000u) : ~m2);
    const int i2 = (int)(NK - 1) - (int)(kk.y & 511u);

    if (v1 - v2 <= DELTA) {  // near-tie: exact fp32 rescore of both candidates
        const float* e = E + (size_t)n * ND;
        const float* c1p = Cg + (size_t)i1 * ND;
        const float* c2p = Cg + (size_t)i2 * ND;
        float d1 = 0.f, d2 = 0.f;
        for (int d = 0; d < ND; d += 4) {
            float4 ev = *(const float4*)(e + d);
            float4 cv1 = *(const float4*)(c1p + d);
            float4 cv2 = *(const float4*)(c2p + d);
            d1 += ev.x * cv1.x + ev.y * cv1.y + ev.z * cv1.z + ev.w * cv1.w;
            d2 += ev.x * cv2.x + ev.y * cv2.y + ev.z * cv2.z + ev.w * cv2.w;
        }
        const float s1 = csq[i1] - 2.f * d1;
        const float s2 = csq[i2] - 2.f * d2;
        if (s2 > s1 || (s2 == s1 && i2 < i1)) { v1 = s2; i1 = i2; } else { v1 = s1; }
    }
    out[1 + n] = (float)i1;
    float s = v1;
#pragma unroll
    for (int mk = 1; mk <= 32; mk <<= 1) s += __shfl_xor(s, mk, 64);
    __shared__ float wsm[4];
    const int lane = threadIdx.x & 63, wd = threadIdx.x >> 6;
    if (lane == 0) wsm[wd] = s;
    __syncthreads();
    if (threadIdx.x == 0) sum2[blockIdx.x] = wsm[0] + wsm[1] + wsm[2] + wsm[3];
}

// ---------------- final: loss = lambda^2 * (sum e^2 + sum row maxima) --------
__global__ __launch_bounds__(256) void final_kernel(const float* __restrict__ e2s,
                                                    const float* __restrict__ sum2,
                                                    float* __restrict__ out) {
    float s = 0.f;
    for (int i = threadIdx.x; i < 4096; i += 256) s += e2s[i];
    for (int i = threadIdx.x; i < 512; i += 256) s += sum2[i];
#pragma unroll
    for (int mk = 1; mk <= 32; mk <<= 1) s += __shfl_xor(s, mk, 64);
    __shared__ float wsm[4];
    const int lane = threadIdx.x & 63, wd = threadIdx.x >> 6;
    if (lane == 0) wsm[wd] = s;
    __syncthreads();
    if (threadIdx.x == 0) out[0] = LM2 * (wsm[0] + wsm[1] + wsm[2] + wsm[3]);
}

extern "C" void kernel_launch(void* const* d_in, const int* in_sizes, int n_in,
                              void* d_out, int out_size, void* d_ws, size_t ws_size,
                              hipStream_t stream) {
    (void)n_in; (void)out_size; (void)ws_size;
    const float* E = (const float*)d_in[0];
    const float* Cg = (const float*)d_in[1];
    float* out = (float*)d_out;

    // ws (floats): csq[512] | e2s[4096] | sum2[512] | Cf16 (256KB) | partials (1MB)
    float* wsf = (float*)d_ws;
    float* csq = wsf;
    float* e2s = wsf + 512;
    float* sum2 = wsf + 4608;
    unsigned short* Cf = (unsigned short*)(wsf + 5120);
    uint2* partials = (uint2*)(wsf + 5120 + 65536);

    const int N = in_sizes[0] / ND;  // 131072
    const int nblk = N >> 7;         // 1024

    prep_kernel<<<NK, 64, 0, stream>>>(Cg, csq, Cf);
    kmeans_mfma<<<nblk, 256, 0, stream>>>(E, Cf, csq, partials, e2s);
    combine_kernel<<<N / 256, 256, 0, stream>>>(partials, csq, E, Cg, out, sum2);
    final_kernel<<<1, 256, 0, stream>>>(e2s, sum2, out);
}

// Round 10
// 104.759 us; speedup vs baseline: 4.1895x; 1.0368x over previous
//
#include <hip/hip_runtime.h>

#define ND 256       // embedding dim
#define NK 512       // centroids
#define LM2 0.0625f  // lambda^2
#define DELTA 0.25f  // approx top-2 gap below this -> exact fp32 rescore

typedef _Float16 f16x8 __attribute__((ext_vector_type(8)));
typedef float f32x4 __attribute__((ext_vector_type(4)));
typedef unsigned short u16x8 __attribute__((ext_vector_type(8)));
typedef unsigned short u16x4 __attribute__((ext_vector_type(4)));

// async 16B global->LDS (zero VGPR staging). LDS dest is wave-uniform base;
// HW adds lane*16. Global src is per-lane.
#define GLD16(GSRC, LDST)                                                      \
    __builtin_amdgcn_global_load_lds(                                         \
        (const __attribute__((address_space(1))) void*)(GSRC),                \
        (__attribute__((address_space(3))) void*)(LDST), 16, 0, 0)

// ---------------- prep: csq[k] + fp16 centroids in per-64col-panel frag order --
// Cf layout: [panel 8][krow 32][col 64][8], krow = (d>>5)*4 + ((d>>3)&3).
// 16B granule = one lane's B-frag slice (measured 0 bank conflicts r4-r9).
__global__ __launch_bounds__(64) void prep_kernel(const float* __restrict__ Cg,
                                                  float* __restrict__ csq,
                                                  unsigned short* __restrict__ Cf) {
    const int k = blockIdx.x, lane = threadIdx.x;
    float4 v = *(const float4*)(Cg + (size_t)k * ND + lane * 4);
    float s = v.x * v.x + v.y * v.y + v.z * v.z + v.w * v.w;
#pragma unroll
    for (int m = 1; m <= 32; m <<= 1) s += __shfl_xor(s, m, 64);
    if (lane == 0) csq[k] = s;
    u16x4 h;
    h[0] = __builtin_bit_cast(unsigned short, (_Float16)v.x);
    h[1] = __builtin_bit_cast(unsigned short, (_Float16)v.y);
    h[2] = __builtin_bit_cast(unsigned short, (_Float16)v.z);
    h[3] = __builtin_bit_cast(unsigned short, (_Float16)v.w);
    const int panel = k >> 6, col = k & 63;
    const int krow = (lane >> 3) * 4 + ((lane >> 1) & 3);  // d0 = lane*4
    const size_t idx = ((size_t)panel << 14) + ((((size_t)krow << 6) + col) << 3) + ((lane & 1) << 2);
    *(u16x4*)(Cf + idx) = h;
}

// ---------------- main: 128 rows/block, full-N sweep, gload_lds B panels ----
// grid 1024: E read from HBM exactly once; A in regs (fp16, 64 VGPR), staged in
// CHUNKS of 4 ks (32 VGPR in flight) so transient peak stays under the 128-VGPR
// ceiling -> no scratch spill (r7/r8/r9 all spilled here). B panels (64 cols,
// 32 KB) double-buffered via global_load_lds (zero staging registers), ONE
// barrier per panel (its vmcnt drain = completion wait; loads fly across the
// whole compute phase). Running per-lane u32 top-2 keys; one merge at end.
__global__ __launch_bounds__(256, 2) void kmeans_mfma(
    const float* __restrict__ E, const unsigned short* __restrict__ Cf,
    const float* __restrict__ csq, uint2* __restrict__ partials,
    float* __restrict__ e2s) {
    __shared__ unsigned short Bbuf[2][16384];  // 2 x 32 KB

    const int tid = threadIdx.x;
    const int lane = tid & 63, wid = tid >> 6;
    const int l15 = lane & 15, l4 = lane >> 4;
    const int rowbase = blockIdx.x << 7;
    const int wrow = rowbase + wid * 32;

    // ---- issue panel 0 staging (flies during A-stage) ----
    {
        const unsigned short* gsrc = Cf;
#pragma unroll
        for (int i = 0; i < 8; ++i)
            GLD16(gsrc + (((size_t)(wid * 8 + i) * 64 + lane) << 3),
                  &Bbuf[0][(size_t)(wid * 8 + i) << 9]);
    }

    // ---- A stage, spill-free: per (m, half): 8 loads in flight, then cvt ----
    const float* a0 = E + (size_t)(wrow + l15) * ND + l4 * 8;
    const float* a1 = E + (size_t)(wrow + 16 + l15) * ND + l4 * 8;

    f16x8 A[2][8];  // [m][ks]
    float e2 = 0.f;
#pragma unroll
    for (int m = 0; m < 2; ++m) {
        const float* ap = m ? a1 : a0;
#pragma unroll
        for (int half = 0; half < 2; ++half) {
            float4 t[8];
#pragma unroll
            for (int q = 0; q < 4; ++q) {
                t[q * 2]     = *(const float4*)(ap + (half * 4 + q) * 32);
                t[q * 2 + 1] = *(const float4*)(ap + (half * 4 + q) * 32 + 4);
            }
#pragma unroll
            for (int q = 0; q < 4; ++q) {
                float4 v0 = t[q * 2], v1 = t[q * 2 + 1];
                e2 += v0.x * v0.x + v0.y * v0.y + v0.z * v0.z + v0.w * v0.w +
                      v1.x * v1.x + v1.y * v1.y + v1.z * v1.z + v1.w * v1.w;
                u16x8 h;
                h[0] = __builtin_bit_cast(unsigned short, (_Float16)v0.x);
                h[1] = __builtin_bit_cast(unsigned short, (_Float16)v0.y);
                h[2] = __builtin_bit_cast(unsigned short, (_Float16)v0.z);
                h[3] = __builtin_bit_cast(unsigned short, (_Float16)v0.w);
                h[4] = __builtin_bit_cast(unsigned short, (_Float16)v1.x);
                h[5] = __builtin_bit_cast(unsigned short, (_Float16)v1.y);
                h[6] = __builtin_bit_cast(unsigned short, (_Float16)v1.z);
                h[7] = __builtin_bit_cast(unsigned short, (_Float16)v1.w);
                A[m][half * 4 + q] = __builtin_bit_cast(f16x8, h);
            }
        }
    }

    unsigned k1[2][4], k2[2][4];
#pragma unroll
    for (int m = 0; m < 2; ++m)
#pragma unroll
        for (int j = 0; j < 4; ++j) { k1[m][j] = 0u; k2[m][j] = 0u; }

#pragma unroll 1
    for (int p = 0; p < 8; ++p) {
        __syncthreads();  // drains vmcnt: panel p staged; buf[(p+1)&1] free
        if (p < 7) {      // issue next panel (lands during this panel's compute)
            const unsigned short* gsrc = Cf + ((size_t)(p + 1) << 14);
            unsigned short* ldst = (unsigned short*)Bbuf[(p + 1) & 1];
#pragma unroll
            for (int i = 0; i < 8; ++i)
                GLD16(gsrc + (((size_t)(wid * 8 + i) * 64 + lane) << 3),
                      &ldst[(size_t)(wid * 8 + i) << 9]);
        }
        float csp[4];
        unsigned ck[4];
#pragma unroll
        for (int n = 0; n < 4; ++n) {
            const int col = (p << 6) + n * 16 + l15;
            csp[n] = csq[col];
            ck[n] = (unsigned)(NK - 1 - col);
        }
        // compute current panel: 8 ks x {4 B-frag ds_read_b128, 8 MFMA}
        const unsigned short* cur = Bbuf[p & 1];
        f32x4 acc[2][4] = {};
#pragma unroll
        for (int ks = 0; ks < 8; ++ks) {
            u16x8 bf[4];
#pragma unroll
            for (int n = 0; n < 4; ++n)
                bf[n] = *(const u16x8*)&cur[(size_t)((((ks << 2) + l4) << 6) + n * 16 + l15) << 3];
#pragma unroll
            for (int m = 0; m < 2; ++m)
#pragma unroll
                for (int n = 0; n < 4; ++n)
                    acc[m][n] = __builtin_amdgcn_mfma_f32_16x16x32_f16(
                        A[m][ks], __builtin_bit_cast(f16x8, bf[n]), acc[m][n], 0, 0, 0);
        }
        // fold panel into running per-lane u32 top-2 keys
        // key = mono(score) with low 9 bits = 511-col (chop err ~5e-3 << DELTA)
#pragma unroll
        for (int m = 0; m < 2; ++m)
#pragma unroll
            for (int j = 0; j < 4; ++j)
#pragma unroll
                for (int n = 0; n < 4; ++n) {
                    const float s = fmaf(-2.f, acc[m][n][j], csp[n]);
                    const unsigned b = __builtin_bit_cast(unsigned, s);
                    const unsigned mono = b ^ ((unsigned)((int)b >> 31) | 0x80000000u);
                    const unsigned key = (mono & 0xFFFFFE00u) | ck[n];
                    const unsigned mn = min(k1[m][j], key);
                    k1[m][j] = max(k1[m][j], key);
                    k2[m][j] = max(k2[m][j], mn);
                }
    }

    // ---- single end-of-block merge across the 16 l15 lanes ----
#pragma unroll
    for (int m = 0; m < 2; ++m)
#pragma unroll
        for (int j = 0; j < 4; ++j) {
            unsigned a = k1[m][j], b2 = k2[m][j];
#pragma unroll
            for (int mk = 1; mk <= 8; mk <<= 1) {
                const unsigned oa = __shfl_xor(a, mk, 64);
                const unsigned ob = __shfl_xor(b2, mk, 64);
                const unsigned mn = min(a, oa);
                a = max(a, oa);
                b2 = max(max(b2, ob), mn);
            }
            if (l15 == 0) {
                const int row = wrow + m * 16 + l4 * 4 + j;
                uint2 o;
                o.x = a;
                o.y = b2;
                partials[row] = o;
            }
        }

    // ---- e2 partial (each row counted exactly once chip-wide) ----
#pragma unroll
    for (int mk = 1; mk <= 32; mk <<= 1) e2 += __shfl_xor(e2, mk, 64);
    if (lane == 0) e2s[blockIdx.x * 4 + wid] = e2;
}

// ---------------- combine: decode top-2 keys, rescore near-ties --------------
__global__ __launch_bounds__(256) void combine_kernel(
    const uint2* __restrict__ partials, const float* __restrict__ csq,
    const float* __restrict__ E, const float* __restrict__ Cg,
    float* __restrict__ out, float* __restrict__ sum2) {
    const int n = blockIdx.x * 256 + threadIdx.x;
    const uint2 kk = partials[n];
    const unsigned m1 = kk.x & 0xFFFFFE00u;
    float v1 = __builtin_bit_cast(float, (m1 & 0x80000000u) ? (m1 ^ 0x80000000u) : ~m1);
    int i1 = (int)(NK - 1) - (int)(kk.x & 511u);
    const unsigned m2 = kk.y & 0xFFFFFE00u;
    const float v2 = __builtin_bit_cast(float, (m2 & 0x80000000u) ? (m2 ^ 0x80000000u) : ~m2);
    const int i2 = (int)(NK - 1) - (int)(kk.y & 511u);

    if (v1 - v2 <= DELTA) {  // near-tie: exact fp32 rescore of both candidates
        const float* e = E + (size_t)n * ND;
        const float* c1p = Cg + (size_t)i1 * ND;
        const float* c2p = Cg + (size_t)i2 * ND;
        float d1 = 0.f, d2 = 0.f;
        for (int d = 0; d < ND; d += 4) {
            float4 ev = *(const float4*)(e + d);
            float4 cv1 = *(const float4*)(c1p + d);
            float4 cv2 = *(const float4*)(c2p + d);
            d1 += ev.x * cv1.x + ev.y * cv1.y + ev.z * cv1.z + ev.w * cv1.w;
            d2 += ev.x * cv2.x + ev.y * cv2.y + ev.z * cv2.z + ev.w * cv2.w;
        }
        const float s1 = csq[i1] - 2.f * d1;
        const float s2 = csq[i2] - 2.f * d2;
        if (s2 > s1 || (s2 == s1 && i2 < i1)) { v1 = s2; i1 = i2; } else { v1 = s1; }
    }
    out[1 + n] = (float)i1;
    float s = v1;
#pragma unroll
    for (int mk = 1; mk <= 32; mk <<= 1) s += __shfl_xor(s, mk, 64);
    __shared__ float wsm[4];
    const int lane = threadIdx.x & 63, wd = threadIdx.x >> 6;
    if (lane == 0) wsm[wd] = s;
    __syncthreads();
    if (threadIdx.x == 0) sum2[blockIdx.x] = wsm[0] + wsm[1] + wsm[2] + wsm[3];
}

// ---------------- final: loss = lambda^2 * (sum e^2 + sum row maxima) --------
__global__ __launch_bounds__(256) void final_kernel(const float* __restrict__ e2s,
                                                    const float* __restrict__ sum2,
                                                    float* __restrict__ out) {
    float s = 0.f;
    for (int i = threadIdx.x; i < 4096; i += 256) s += e2s[i];
    for (int i = threadIdx.x; i < 512; i += 256) s += sum2[i];
#pragma unroll
    for (int mk = 1; mk <= 32; mk <<= 1) s += __shfl_xor(s, mk, 64);
    __shared__ float wsm[4];
    const int lane = threadIdx.x & 63, wd = threadIdx.x >> 6;
    if (lane == 0) wsm[wd] = s;
    __syncthreads();
    if (threadIdx.x == 0) out[0] = LM2 * (wsm[0] + wsm[1] + wsm[2] + wsm[3]);
}

extern "C" void kernel_launch(void* const* d_in, const int* in_sizes, int n_in,
                              void* d_out, int out_size, void* d_ws, size_t ws_size,
                              hipStream_t stream) {
    (void)n_in; (void)out_size; (void)ws_size;
    const float* E = (const float*)d_in[0];
    const float* Cg = (const float*)d_in[1];
    float* out = (float*)d_out;

    // ws (floats): csq[512] | e2s[4096] | sum2[512] | Cf16 (256KB) | partials (1MB)
    float* wsf = (float*)d_ws;
    float* csq = wsf;
    float* e2s = wsf + 512;
    float* sum2 = wsf + 4608;
    unsigned short* Cf = (unsigned short*)(wsf + 5120);
    uint2* partials = (uint2*)(wsf + 5120 + 65536);

    const int N = in_sizes[0] / ND;  // 131072
    const int nblk = N >> 7;         // 1024

    prep_kernel<<<NK, 64, 0, stream>>>(Cg, csq, Cf);
    kmeans_mfma<<<nblk, 256, 0, stream>>>(E, Cf, csq, partials, e2s);
    combine_kernel<<<N / 256, 256, 0, stream>>>(partials, csq, E, Cg, out, sum2);
    final_kernel<<<1, 256, 0, stream>>>(e2s, sum2, out);
}

// Round 11
// 100.173 us; speedup vs baseline: 4.3813x; 1.0458x over previous
//
#include <hip/hip_runtime.h>

#define ND 256       // embedding dim
#define NK 512       // centroids
#define LM2 0.0625f  // lambda^2
#define DELTA 0.25f  // approx top-2 gap below this -> exact fp32 rescore

typedef _Float16 f16x8 __attribute__((ext_vector_type(8)));
typedef float f32x4 __attribute__((ext_vector_type(4)));
typedef unsigned short u16x8 __attribute__((ext_vector_type(8)));
typedef unsigned short u16x4 __attribute__((ext_vector_type(4)));

// async 16B global->LDS (zero VGPR staging). LDS dest is wave-uniform base;
// HW adds lane*16. Global src is per-lane.
#define GLD16(GSRC, LDST)                                                      \
    __builtin_amdgcn_global_load_lds(                                         \
        (const __attribute__((address_space(1))) void*)(GSRC),                \
        (__attribute__((address_space(3))) void*)(LDST), 16, 0, 0)

// ---------------- prep: csq[k] + fp16 centroids in per-64col-panel frag order --
// Cf layout: [panel 8][krow 32][col 64][8], krow = (d>>5)*4 + ((d>>3)&3).
// 16B granule = one lane's B-frag slice (measured 0 bank conflicts r4-r10).
__global__ __launch_bounds__(64) void prep_kernel(const float* __restrict__ Cg,
                                                  float* __restrict__ csq,
                                                  unsigned short* __restrict__ Cf) {
    const int k = blockIdx.x, lane = threadIdx.x;
    float4 v = *(const float4*)(Cg + (size_t)k * ND + lane * 4);
    float s = v.x * v.x + v.y * v.y + v.z * v.z + v.w * v.w;
#pragma unroll
    for (int m = 1; m <= 32; m <<= 1) s += __shfl_xor(s, m, 64);
    if (lane == 0) csq[k] = s;
    u16x4 h;
    h[0] = __builtin_bit_cast(unsigned short, (_Float16)v.x);
    h[1] = __builtin_bit_cast(unsigned short, (_Float16)v.y);
    h[2] = __builtin_bit_cast(unsigned short, (_Float16)v.z);
    h[3] = __builtin_bit_cast(unsigned short, (_Float16)v.w);
    const int panel = k >> 6, col = k & 63;
    const int krow = (lane >> 3) * 4 + ((lane >> 1) & 3);  // d0 = lane*4
    const size_t idx = ((size_t)panel << 14) + ((((size_t)krow << 6) + col) << 3) + ((lane & 1) << 2);
    *(u16x4*)(Cf + idx) = h;
}

// ---------------- main: 8 waves x 16 rows, low-VGPR, gload_lds B panels ------
// grid 1024 x 512 threads: 128 rows/block (16/wave). A-frags are A[8]=32 VGPR
// (vs 64 at 32 rows/wave) -> panel-loop arch peak ~90 regs, fits the 128-reg
// cap at 4 waves/SIMD with NO scratch spill (r7-r10 all spilled here).
// B panels (64 cols, 32 KB) double-buffered via global_load_lds (zero staging
// regs), ONE barrier per panel. Running per-lane u32 top-2 keys; merge at end.
__global__ __launch_bounds__(512, 4) void kmeans_mfma(
    const float* __restrict__ E, const unsigned short* __restrict__ Cf,
    const float* __restrict__ csq, uint2* __restrict__ partials,
    float* __restrict__ e2s) {
    __shared__ unsigned short Bbuf[2][16384];  // 2 x 32 KB

    const int tid = threadIdx.x;
    const int lane = tid & 63, wid = tid >> 6;  // wid 0..7
    const int l15 = lane & 15, l4 = lane >> 4;
    const int rowbase = blockIdx.x << 7;
    const int wrow = rowbase + wid * 16;

    // ---- issue panel 0 staging (flies during A-stage); 4 slots per wave ----
#pragma unroll
    for (int i = 0; i < 4; ++i)
        GLD16(Cf + (((size_t)(wid * 4 + i) * 64 + lane) << 3),
              &Bbuf[0][(size_t)(wid * 4 + i) << 9]);

    // ---- A stage: one row per l15 lane-group, 2 chunks of 4 ks ----
    const float* ap = E + (size_t)(wrow + l15) * ND + l4 * 8;

    f16x8 A[8];  // [ks], 32 VGPR
    float e2 = 0.f;
#pragma unroll
    for (int half = 0; half < 2; ++half) {
        float4 t[8];
#pragma unroll
        for (int q = 0; q < 4; ++q) {
            t[q * 2]     = *(const float4*)(ap + (half * 4 + q) * 32);
            t[q * 2 + 1] = *(const float4*)(ap + (half * 4 + q) * 32 + 4);
        }
#pragma unroll
        for (int q = 0; q < 4; ++q) {
            float4 v0 = t[q * 2], v1 = t[q * 2 + 1];
            e2 += v0.x * v0.x + v0.y * v0.y + v0.z * v0.z + v0.w * v0.w +
                  v1.x * v1.x + v1.y * v1.y + v1.z * v1.z + v1.w * v1.w;
            u16x8 h;
            h[0] = __builtin_bit_cast(unsigned short, (_Float16)v0.x);
            h[1] = __builtin_bit_cast(unsigned short, (_Float16)v0.y);
            h[2] = __builtin_bit_cast(unsigned short, (_Float16)v0.z);
            h[3] = __builtin_bit_cast(unsigned short, (_Float16)v0.w);
            h[4] = __builtin_bit_cast(unsigned short, (_Float16)v1.x);
            h[5] = __builtin_bit_cast(unsigned short, (_Float16)v1.y);
            h[6] = __builtin_bit_cast(unsigned short, (_Float16)v1.z);
            h[7] = __builtin_bit_cast(unsigned short, (_Float16)v1.w);
            A[half * 4 + q] = __builtin_bit_cast(f16x8, h);
        }
    }

    unsigned k1[4], k2[4];
#pragma unroll
    for (int j = 0; j < 4; ++j) { k1[j] = 0u; k2[j] = 0u; }

#pragma unroll 1
    for (int p = 0; p < 8; ++p) {
        __syncthreads();  // drains own vmcnt before barrier: panel p staged
        if (p < 7) {      // issue next panel (lands during this panel's compute)
            const unsigned short* gsrc = Cf + ((size_t)(p + 1) << 14);
            unsigned short* ldst = (unsigned short*)Bbuf[(p + 1) & 1];
#pragma unroll
            for (int i = 0; i < 4; ++i)
                GLD16(gsrc + (((size_t)(wid * 4 + i) * 64 + lane) << 3),
                      &ldst[(size_t)(wid * 4 + i) << 9]);
        }
        float csp[4];
        unsigned ck[4];
#pragma unroll
        for (int n = 0; n < 4; ++n) {
            const int col = (p << 6) + n * 16 + l15;
            csp[n] = csq[col];
            ck[n] = (unsigned)(NK - 1 - col);
        }
        // compute current panel: 8 ks x {4 B-frag ds_read_b128, 4 MFMA}
        const unsigned short* cur = Bbuf[p & 1];
        f32x4 acc[4] = {};
#pragma unroll
        for (int ks = 0; ks < 8; ++ks) {
            u16x8 bf[4];
#pragma unroll
            for (int n = 0; n < 4; ++n)
                bf[n] = *(const u16x8*)&cur[(size_t)((((ks << 2) + l4) << 6) + n * 16 + l15) << 3];
#pragma unroll
            for (int n = 0; n < 4; ++n)
                acc[n] = __builtin_amdgcn_mfma_f32_16x16x32_f16(
                    A[ks], __builtin_bit_cast(f16x8, bf[n]), acc[n], 0, 0, 0);
        }
        // fold panel into running per-lane u32 top-2 keys
        // key = mono(score) with low 9 bits = 511-col (chop err ~5e-3 << DELTA)
#pragma unroll
        for (int j = 0; j < 4; ++j)
#pragma unroll
            for (int n = 0; n < 4; ++n) {
                const float s = fmaf(-2.f, acc[n][j], csp[n]);
                const unsigned b = __builtin_bit_cast(unsigned, s);
                const unsigned mono = b ^ ((unsigned)((int)b >> 31) | 0x80000000u);
                const unsigned key = (mono & 0xFFFFFE00u) | ck[n];
                const unsigned mn = min(k1[j], key);
                k1[j] = max(k1[j], key);
                k2[j] = max(k2[j], mn);
            }
    }

    // ---- single end-of-block merge across the 16 l15 lanes ----
#pragma unroll
    for (int j = 0; j < 4; ++j) {
        unsigned a = k1[j], b2 = k2[j];
#pragma unroll
        for (int mk = 1; mk <= 8; mk <<= 1) {
            const unsigned oa = __shfl_xor(a, mk, 64);
            const unsigned ob = __shfl_xor(b2, mk, 64);
            const unsigned mn = min(a, oa);
            a = max(a, oa);
            b2 = max(max(b2, ob), mn);
        }
        if (l15 == 0) {
            const int row = wrow + l4 * 4 + j;
            uint2 o;
            o.x = a;
            o.y = b2;
            partials[row] = o;
        }
    }

    // ---- e2 partial (each row counted exactly once chip-wide) ----
#pragma unroll
    for (int mk = 1; mk <= 32; mk <<= 1) e2 += __shfl_xor(e2, mk, 64);
    if (lane == 0) e2s[blockIdx.x * 8 + wid] = e2;
}

// ---------------- combine: decode top-2 keys, rescore near-ties --------------
__global__ __launch_bounds__(256) void combine_kernel(
    const uint2* __restrict__ partials, const float* __restrict__ csq,
    const float* __restrict__ E, const float* __restrict__ Cg,
    float* __restrict__ out, float* __restrict__ sum2) {
    const int n = blockIdx.x * 256 + threadIdx.x;
    const uint2 kk = partials[n];
    const unsigned m1 = kk.x & 0xFFFFFE00u;
    float v1 = __builtin_bit_cast(float, (m1 & 0x80000000u) ? (m1 ^ 0x80000000u) : ~m1);
    int i1 = (int)(NK - 1) - (int)(kk.x & 511u);
    const unsigned m2 = kk.y & 0xFFFFFE00u;
    const float v2 = __builtin_bit_cast(float, (m2 & 0x80000000u) ? (m2 ^ 0x80000000u) : ~m2);
    const int i2 = (int)(NK - 1) - (int)(kk.y & 511u);

    if (v1 - v2 <= DELTA) {  // near-tie: exact fp32 rescore of both candidates
        const float* e = E + (size_t)n * ND;
        const float* c1p = Cg + (size_t)i1 * ND;
        const float* c2p = Cg + (size_t)i2 * ND;
        float d1 = 0.f, d2 = 0.f;
        for (int d = 0; d < ND; d += 4) {
            float4 ev = *(const float4*)(e + d);
            float4 cv1 = *(const float4*)(c1p + d);
            float4 cv2 = *(const float4*)(c2p + d);
            d1 += ev.x * cv1.x + ev.y * cv1.y + ev.z * cv1.z + ev.w * cv1.w;
            d2 += ev.x * cv2.x + ev.y * cv2.y + ev.z * cv2.z + ev.w * cv2.w;
        }
        const float s1 = csq[i1] - 2.f * d1;
        const float s2 = csq[i2] - 2.f * d2;
        if (s2 > s1 || (s2 == s1 && i2 < i1)) { v1 = s2; i1 = i2; } else { v1 = s1; }
    }
    out[1 + n] = (float)i1;
    float s = v1;
#pragma unroll
    for (int mk = 1; mk <= 32; mk <<= 1) s += __shfl_xor(s, mk, 64);
    __shared__ float wsm[4];
    const int lane = threadIdx.x & 63, wd = threadIdx.x >> 6;
    if (lane == 0) wsm[wd] = s;
    __syncthreads();
    if (threadIdx.x == 0) sum2[blockIdx.x] = wsm[0] + wsm[1] + wsm[2] + wsm[3];
}

// ---------------- final: loss = lambda^2 * (sum e^2 + sum row maxima) --------
__global__ __launch_bounds__(256) void final_kernel(const float* __restrict__ e2s,
                                                    const float* __restrict__ sum2,
                                                    float* __restrict__ out) {
    float s = 0.f;
    for (int i = threadIdx.x; i < 8192; i += 256) s += e2s[i];
    for (int i = threadIdx.x; i < 512; i += 256) s += sum2[i];
#pragma unroll
    for (int mk = 1; mk <= 32; mk <<= 1) s += __shfl_xor(s, mk, 64);
    __shared__ float wsm[4];
    const int lane = threadIdx.x & 63, wd = threadIdx.x >> 6;
    if (lane == 0) wsm[wd] = s;
    __syncthreads();
    if (threadIdx.x == 0) out[0] = LM2 * (wsm[0] + wsm[1] + wsm[2] + wsm[3]);
}

extern "C" void kernel_launch(void* const* d_in, const int* in_sizes, int n_in,
                              void* d_out, int out_size, void* d_ws, size_t ws_size,
                              hipStream_t stream) {
    (void)n_in; (void)out_size; (void)ws_size;
    const float* E = (const float*)d_in[0];
    const float* Cg = (const float*)d_in[1];
    float* out = (float*)d_out;

    // ws (floats): csq[512] | e2s[8192] | sum2[512] | Cf16 (256KB) | partials (1MB)
    float* wsf = (float*)d_ws;
    float* csq = wsf;
    float* e2s = wsf + 512;
    float* sum2 = wsf + 8704;
    unsigned short* Cf = (unsigned short*)(wsf + 9216);
    uint2* partials = (uint2*)(wsf + 9216 + 65536);

    const int N = in_sizes[0] / ND;  // 131072
    const int nblk = N >> 7;         // 1024

    prep_kernel<<<NK, 64, 0, stream>>>(Cg, csq, Cf);
    kmeans_mfma<<<nblk, 512, 0, stream>>>(E, Cf, csq, partials, e2s);
    combine_kernel<<<N / 256, 256, 0, stream>>>(partials, csq, E, Cg, out, sum2);
    final_kernel<<<1, 256, 0, stream>>>(e2s, sum2, out);
}